// Round 5
// baseline (615.412 us; speedup 1.0000x reference)
//
#include <hip/hip_runtime.h>
#include <hip/hip_bf16.h>
#include <hip/hip_cooperative_groups.h>

namespace cg = cooperative_groups;

typedef __attribute__((ext_vector_type(8))) short short8;
typedef __attribute__((ext_vector_type(8))) unsigned short ushort8v;
typedef __attribute__((ext_vector_type(4))) unsigned short ushort4v;
typedef __attribute__((ext_vector_type(4))) float f32x4;

__device__ __forceinline__ unsigned short f2bf(float f) {
    union { float f; unsigned int u; } v; v.f = f;
    unsigned int r = v.u + 0x7FFFu + ((v.u >> 16) & 1u);
    return (unsigned short)(r >> 16);
}
__device__ __forceinline__ float bf2f(unsigned short u) {
    union { unsigned int i; float f; } v; v.i = ((unsigned int)u) << 16;
    return v.f;
}

// prep: blocks [0,64) permute W1/W2 into MFMA-fragment-linear bf16;
//       blocks [64,..) convert x -> bf16 (8 elems/thread).
__global__ __launch_bounds__(256) void prep_kernel(
    const float* __restrict__ W1, const float* __restrict__ W2,
    const float* __restrict__ x,
    unsigned short* __restrict__ wtf1, unsigned short* __restrict__ wtf2,
    unsigned short* __restrict__ xb, int n8)
{
    int bid = blockIdx.x;
    if (bid < 64) {
        int t = bid * 256 + threadIdx.x;   // 0..16383
        int k = t >> 7, j = t & 127;
        int jt = j >> 4, r = j & 15, kt = k >> 5, kg = (k >> 3) & 3, e = k & 7;
        int flin = (jt * 4 + kt) * 512 + (kg * 16 + r) * 8 + e;
        wtf1[flin] = f2bf(W1[t]);
        wtf2[flin] = f2bf(W2[t]);
        return;
    }
    int t = (bid - 64) * 256 + threadIdx.x;
    if (t >= n8) return;
    float4 x0 = reinterpret_cast<const float4*>(x)[(size_t)t * 2];
    float4 x1 = reinterpret_cast<const float4*>(x)[(size_t)t * 2 + 1];
    ushort8v o;
    o[0] = f2bf(x0.x); o[1] = f2bf(x0.y); o[2] = f2bf(x0.z); o[3] = f2bf(x0.w);
    o[4] = f2bf(x1.x); o[5] = f2bf(x1.y); o[6] = f2bf(x1.z); o[7] = f2bf(x1.w);
    reinterpret_cast<ushort8v*>(xb)[t] = o;
}

// One cooperative kernel: zero -> hist -> chunk scan -> chunk-sum scan ->
// offsets+cursor -> CSR scatter. 1024 blocks x 256 (4 blocks/CU, co-resident).
__global__ __launch_bounds__(256) void csr_kernel(
    const int* __restrict__ src, const int* __restrict__ dst,
    const float* __restrict__ ew,
    int* __restrict__ offs, int* __restrict__ cursor, int* __restrict__ bsums,
    int* __restrict__ srcs, float* __restrict__ wsrt,
    int N, int E, int nchunk)
{
    cg::grid_group grid = cg::this_grid();
    __shared__ int tsum[256];
    const int G = gridDim.x;
    const int tid = threadIdx.x, bid = blockIdx.x;
    const int gthreads = G * 256;
    const int gt = bid * 256 + tid;

    // phase0: zero offs[0..N]
    for (int i = gt; i <= N; i += gthreads) offs[i] = 0;
    grid.sync();

    // phase1: degree histogram
    for (int e = gt; e < E; e += gthreads) atomicAdd(&offs[dst[e]], 1);
    grid.sync();

    // phase2: per-1024-chunk local exclusive scan (in place) + chunk totals
    for (int c = bid; c < nchunk; c += G) {
        int base = c * 1024 + tid * 4;
        int v[4]; int tl = 0;
        #pragma unroll
        for (int j = 0; j < 4; ++j) {
            v[j] = (base + j < N) ? offs[base + j] : 0;
            tl += v[j];
        }
        tsum[tid] = tl; __syncthreads();
        for (int off = 1; off < 256; off <<= 1) {
            int u = (tid >= off) ? tsum[tid - off] : 0;
            __syncthreads();
            tsum[tid] += u;
            __syncthreads();
        }
        int run = tsum[tid] - tl;
        #pragma unroll
        for (int j = 0; j < 4; ++j) {
            if (base + j < N) offs[base + j] = run;
            run += v[j];
        }
        if (tid == 255) bsums[c] = tsum[255];
        __syncthreads();
    }
    grid.sync();

    // phase3: block 0 exclusive-scans the chunk totals (nchunk <= 256)
    if (bid == 0) {
        int v = (tid < nchunk) ? bsums[tid] : 0;
        tsum[tid] = v; __syncthreads();
        for (int off = 1; off < 256; off <<= 1) {
            int u = (tid >= off) ? tsum[tid - off] : 0;
            __syncthreads();
            tsum[tid] += u;
            __syncthreads();
        }
        if (tid < nchunk) bsums[tid] = tsum[tid] - v;
    }
    grid.sync();

    // phase4: add chunk offsets, fill cursor, cap
    for (int i = gt; i < N; i += gthreads) {
        int v = offs[i] + bsums[i >> 10];
        offs[i] = v;
        cursor[i] = v;
    }
    if (gt == 0) offs[N] = E;
    grid.sync();

    // phase5: scatter (src, w) into CSR slots
    for (int e = gt; e < E; e += gthreads) {
        int pos = atomicAdd(&cursor[dst[e]], 1);
        srcs[pos] = src[e];
        wsrt[pos] = ew[e];
    }
}

// ---- Fused: CSR gather (bf16 x, 8 loads in flight) -> LDS -> 2x MFMA -> y ----
__global__ __launch_bounds__(256) void fused_kernel(
    const unsigned short* __restrict__ xb, const int* __restrict__ offs,
    const int* __restrict__ srcs, const float* __restrict__ wsrt,
    const unsigned short* __restrict__ wtf1,
    const unsigned short* __restrict__ wtf2,
    const float* __restrict__ b1, const float* __restrict__ b2,
    float* __restrict__ y, int N)
{
    __shared__ __align__(16) unsigned short Hs[64 * 128];
    int tid = threadIdx.x;
    int node0 = blockIdx.x * 64;

    // Phase 1: gather. 8 groups x 32 lanes; group g does rows {g, g+8, ...}.
    // Lane l holds elems 4l..4l+3 (8B bf16 load -> 256B/row coalesced).
    {
        int g = tid >> 5, l = tid & 31;
        const ushort4v* xr = reinterpret_cast<const ushort4v*>(xb);
        for (int it = 0; it < 8; ++it) {
            int m = it * 8 + g;
            int node = node0 + m;
            float4 acc = {0.f, 0.f, 0.f, 0.f};
            if (node < N) {
                ushort4v sx = xr[(size_t)node * 32 + l];   // self-term (EPS=0)
                acc.x = bf2f(sx[0]); acc.y = bf2f(sx[1]);
                acc.z = bf2f(sx[2]); acc.w = bf2f(sx[3]);
                int s = offs[node], e = offs[node + 1];
                for (int base = s; base < e; base += 32) {
                    int cnt = min(e - base, 32);
                    int sv = 0; float wv = 0.f;            // pad: row 0, w=0
                    if (l < cnt) { sv = srcs[base + l]; wv = wsrt[base + l]; }
                    for (int j = 0; j < cnt; j += 8) {
                        ushort4v v[8]; float w[8];
                        #pragma unroll
                        for (int q = 0; q < 8; ++q) {
                            int sq = __shfl(sv, j + q, 32);
                            w[q] = __shfl(wv, j + q, 32);
                            v[q] = xr[(size_t)sq * 32 + l];
                        }
                        #pragma unroll
                        for (int q = 0; q < 8; ++q) {
                            acc.x += w[q] * bf2f(v[q][0]);
                            acc.y += w[q] * bf2f(v[q][1]);
                            acc.z += w[q] * bf2f(v[q][2]);
                            acc.w += w[q] * bf2f(v[q][3]);
                        }
                    }
                }
            }
            ushort4v o;
            o[0] = f2bf(acc.x); o[1] = f2bf(acc.y);
            o[2] = f2bf(acc.z); o[3] = f2bf(acc.w);
            int soff = m * 128 + (((l >> 1) ^ (m & 7)) << 3) + ((l & 1) << 2);
            *reinterpret_cast<ushort4v*>(&Hs[soff]) = o;
        }
    }
    __syncthreads();

    int wave = tid >> 6, lane = tid & 63;
    int r = lane & 15, kg = lane >> 4;
    int row0 = node0 + wave * 16;
    int mr = wave * 16 + r;

    short8 a[4];
    #pragma unroll
    for (int kt = 0; kt < 4; ++kt)
        a[kt] = *reinterpret_cast<const short8*>(
            &Hs[mr * 128 + (((kt * 4 + kg) ^ (r & 7)) << 3)]);

    f32x4 acc1[8];
    #pragma unroll
    for (int jt = 0; jt < 8; ++jt) acc1[jt] = {0.f, 0.f, 0.f, 0.f};

    #pragma unroll
    for (int jt = 0; jt < 8; ++jt) {
        #pragma unroll
        for (int kt = 0; kt < 4; ++kt) {
            short8 b = *reinterpret_cast<const short8*>(
                wtf1 + ((jt * 4 + kt) << 9) + (lane << 3));   // coalesced
            acc1[jt] = __builtin_amdgcn_mfma_f32_16x16x32_bf16(a[kt], b, acc1[jt], 0, 0, 0);
        }
    }

    #pragma unroll
    for (int jt = 0; jt < 8; ++jt) {
        float bias = b1[jt * 16 + r];
        int col = jt * 16 + r;
        #pragma unroll
        for (int reg = 0; reg < 4; ++reg) {
            int m2 = wave * 16 + kg * 4 + reg;
            float h = fmaxf(acc1[jt][reg] + bias, 0.0f);
            Hs[m2 * 128 + (((col >> 3) ^ (m2 & 7)) << 3) + (col & 7)] = f2bf(h);
        }
    }
    __syncthreads();

    short8 a2[4];
    #pragma unroll
    for (int kt = 0; kt < 4; ++kt)
        a2[kt] = *reinterpret_cast<const short8*>(
            &Hs[mr * 128 + (((kt * 4 + kg) ^ (r & 7)) << 3)]);

    f32x4 acc2[8];
    #pragma unroll
    for (int jt = 0; jt < 8; ++jt) acc2[jt] = {0.f, 0.f, 0.f, 0.f};

    #pragma unroll
    for (int jt = 0; jt < 8; ++jt) {
        #pragma unroll
        for (int kt = 0; kt < 4; ++kt) {
            short8 b = *reinterpret_cast<const short8*>(
                wtf2 + ((jt * 4 + kt) << 9) + (lane << 3));
            acc2[jt] = __builtin_amdgcn_mfma_f32_16x16x32_bf16(a2[kt], b, acc2[jt], 0, 0, 0);
        }
    }

    #pragma unroll
    for (int jt = 0; jt < 8; ++jt) {
        float bias = b2[jt * 16 + r];
        #pragma unroll
        for (int reg = 0; reg < 4; ++reg) {
            int orow = row0 + kg * 4 + reg;
            if (orow < N)
                y[(size_t)orow * 128 + jt * 16 + r] = acc2[jt][reg] + bias;
        }
    }
}

extern "C" void kernel_launch(void* const* d_in, const int* in_sizes, int n_in,
                              void* d_out, int out_size, void* d_ws, size_t ws_size,
                              hipStream_t stream) {
    const float* x  = (const float*)d_in[0];
    const int*   ei = (const int*)d_in[1];      // [2,E] as int32
    const float* ew = (const float*)d_in[2];
    const float* W1 = (const float*)d_in[3];
    const float* b1 = (const float*)d_in[4];
    const float* W2 = (const float*)d_in[5];
    const float* b2 = (const float*)d_in[6];
    float* y = (float*)d_out;

    int N = in_sizes[0] / 128;   // 100000
    int E = in_sizes[2];         // 600000
    const size_t ND = (size_t)N * 128;
    int nchunk = (N + 1023) / 1024;   // 98
    int n8 = (int)(ND / 8);

    char* ws = (char*)d_ws;
    size_t off = 0;
    auto bump = [&](size_t bytes) {
        void* p = ws + off;
        off += (bytes + 255) & ~(size_t)255;
        return p;
    };
    unsigned short* wtf1   = (unsigned short*)bump(128 * 128 * 2);
    unsigned short* wtf2   = (unsigned short*)bump(128 * 128 * 2);
    unsigned short* xb     = (unsigned short*)bump(ND * 2);          // 25.6 MB
    int*            offs   = (int*)bump((size_t)(N + 1) * 4);
    int*            cursor = (int*)bump((size_t)N * 4);
    int*            bsums  = (int*)bump(1024);
    int*            srcs   = (int*)bump((size_t)E * 4);
    float*          wsrt   = (float*)bump((size_t)E * 4);

    const int* src = ei;
    const int* dst = ei + E;

    prep_kernel<<<64 + (n8 + 255) / 256, 256, 0, stream>>>(
        W1, W2, x, wtf1, wtf2, xb, n8);

    void* cargs[] = {
        (void*)&src, (void*)&dst, (void*)&ew,
        (void*)&offs, (void*)&cursor, (void*)&bsums,
        (void*)&srcs, (void*)&wsrt,
        (void*)&N, (void*)&E, (void*)&nchunk
    };
    hipLaunchCooperativeKernel((const void*)csr_kernel, dim3(1024), dim3(256),
                               cargs, 0, stream);

    fused_kernel<<<(N + 63) / 64, 256, 0, stream>>>(
        xb, offs, srcs, wsrt, wtf1, wtf2, b1, b2, y, N);
}

// Round 6
// 140.254 us; speedup vs baseline: 4.3878x; 4.3878x over previous
//
#include <hip/hip_runtime.h>
#include <hip/hip_bf16.h>

typedef __attribute__((ext_vector_type(8))) short short8;
typedef __attribute__((ext_vector_type(8))) unsigned short ushort8v;
typedef __attribute__((ext_vector_type(4))) unsigned short ushort4v;
typedef __attribute__((ext_vector_type(4))) float f32x4;

__device__ __forceinline__ unsigned short f2bf(float f) {
    union { float f; unsigned int u; } v; v.f = f;
    unsigned int r = v.u + 0x7FFFu + ((v.u >> 16) & 1u);
    return (unsigned short)(r >> 16);
}
__device__ __forceinline__ float bf2f(unsigned short u) {
    union { unsigned int i; float f; } v; v.i = ((unsigned int)u) << 16;
    return v.f;
}

// prep: blocks [0,64)          -> W1/W2 permute to MFMA-fragment-linear bf16
//       blocks [64,64+nxb)     -> x (f32) -> xb (bf16), 8 elems/thread
//       blocks [64+nxb, ...)   -> degree histogram into offs (pre-zeroed)
__global__ __launch_bounds__(256) void prep_kernel(
    const float* __restrict__ W1, const float* __restrict__ W2,
    const float* __restrict__ x, const int* __restrict__ dst,
    unsigned short* __restrict__ wtf1, unsigned short* __restrict__ wtf2,
    unsigned short* __restrict__ xb, int* __restrict__ offs,
    int n8, int E, int nxb)
{
    int bid = blockIdx.x;
    if (bid < 64) {
        int t = bid * 256 + threadIdx.x;   // 0..16383
        int k = t >> 7, j = t & 127;
        int jt = j >> 4, r = j & 15, kt = k >> 5, kg = (k >> 3) & 3, e = k & 7;
        int flin = (jt * 4 + kt) * 512 + (kg * 16 + r) * 8 + e;
        wtf1[flin] = f2bf(W1[t]);
        wtf2[flin] = f2bf(W2[t]);
        return;
    }
    if (bid < 64 + nxb) {
        int t = (bid - 64) * 256 + threadIdx.x;
        if (t >= n8) return;
        float4 x0 = reinterpret_cast<const float4*>(x)[(size_t)t * 2];
        float4 x1 = reinterpret_cast<const float4*>(x)[(size_t)t * 2 + 1];
        ushort8v o;
        o[0] = f2bf(x0.x); o[1] = f2bf(x0.y); o[2] = f2bf(x0.z); o[3] = f2bf(x0.w);
        o[4] = f2bf(x1.x); o[5] = f2bf(x1.y); o[6] = f2bf(x1.z); o[7] = f2bf(x1.w);
        reinterpret_cast<ushort8v*>(xb)[t] = o;
        return;
    }
    int e = (bid - 64 - nxb) * 256 + threadIdx.x;
    if (e < E) atomicAdd(&offs[dst[e]], 1);
}

// Per-1024-chunk exclusive scan in place; LAST finishing block (agent-scope
// done-counter, order-independent) exclusive-scans the chunk totals.
// Final offset of node i is offs[i] + bsums[i>>10], computed by consumers.
__global__ __launch_bounds__(256) void scan_kernel(
    int* __restrict__ offs, int* __restrict__ bsums, int* __restrict__ done,
    int N, int nchunk)
{
    __shared__ int tsum[256];
    __shared__ int amLast;
    int c = blockIdx.x, tid = threadIdx.x;
    int base = c * 1024 + tid * 4;
    int v[4]; int tl = 0;
    #pragma unroll
    for (int j = 0; j < 4; ++j) {
        v[j] = (base + j < N) ? offs[base + j] : 0;
        tl += v[j];
    }
    tsum[tid] = tl; __syncthreads();
    for (int off = 1; off < 256; off <<= 1) {
        int u = (tid >= off) ? tsum[tid - off] : 0;
        __syncthreads();
        tsum[tid] += u;
        __syncthreads();
    }
    int run = tsum[tid] - tl;   // exclusive within chunk
    #pragma unroll
    for (int j = 0; j < 4; ++j) {
        if (base + j < N) offs[base + j] = run;
        run += v[j];
    }
    if (tid == 255) {
        __hip_atomic_store(&bsums[c], tsum[255], __ATOMIC_RELEASE,
                           __HIP_MEMORY_SCOPE_AGENT);
        int prev = __hip_atomic_fetch_add(done, 1, __ATOMIC_ACQ_REL,
                                          __HIP_MEMORY_SCOPE_AGENT);
        amLast = (prev == nchunk - 1);
    }
    __syncthreads();
    if (amLast) {   // uniform per block
        int bv = (tid < nchunk)
            ? __hip_atomic_load(&bsums[tid], __ATOMIC_ACQUIRE,
                                __HIP_MEMORY_SCOPE_AGENT) : 0;
        tsum[tid] = bv; __syncthreads();
        for (int off = 1; off < 256; off <<= 1) {
            int u = (tid >= off) ? tsum[tid - off] : 0;
            __syncthreads();
            tsum[tid] += u;
            __syncthreads();
        }
        if (tid < nchunk)
            __hip_atomic_store(&bsums[tid], tsum[tid] - bv, __ATOMIC_RELEASE,
                               __HIP_MEMORY_SCOPE_AGENT);
    }
}

// Scatter (src, w) packed as int2 into CSR slots. czero is pre-zeroed.
__global__ __launch_bounds__(256) void scatter_kernel(
    const int* __restrict__ src, const int* __restrict__ dst,
    const float* __restrict__ ew, const int* __restrict__ offs,
    const int* __restrict__ bsums, int* __restrict__ czero,
    int2* __restrict__ esrt, int E)
{
    int e = blockIdx.x * 256 + threadIdx.x;
    if (e >= E) return;
    int d = dst[e];
    int pos = offs[d] + bsums[d >> 10] + atomicAdd(&czero[d], 1);
    esrt[pos] = make_int2(src[e], __float_as_int(ew[e]));
}

// ---- Fused: CSR gather (bf16 x, 8 loads in flight) -> LDS -> 2x MFMA -> y ----
__global__ __launch_bounds__(256) void fused_kernel(
    const unsigned short* __restrict__ xb, const int* __restrict__ offs,
    const int* __restrict__ bsums, const int2* __restrict__ esrt,
    const unsigned short* __restrict__ wtf1,
    const unsigned short* __restrict__ wtf2,
    const float* __restrict__ b1, const float* __restrict__ b2,
    float* __restrict__ y, int N, int E)
{
    __shared__ __align__(16) unsigned short Hs[64 * 128];
    int tid = threadIdx.x;
    int node0 = blockIdx.x * 64;

    // Phase 1: gather. 8 groups x 32 lanes; group g does rows {g, g+8, ...}.
    {
        int g = tid >> 5, l = tid & 31;
        const ushort4v* xr = reinterpret_cast<const ushort4v*>(xb);
        for (int it = 0; it < 8; ++it) {
            int m = it * 8 + g;
            int node = node0 + m;
            float4 acc = {0.f, 0.f, 0.f, 0.f};
            if (node < N) {
                ushort4v sx = xr[(size_t)node * 32 + l];   // self-term (EPS=0)
                acc.x = bf2f(sx[0]); acc.y = bf2f(sx[1]);
                acc.z = bf2f(sx[2]); acc.w = bf2f(sx[3]);
                int s = offs[node] + bsums[node >> 10];
                int e = (node + 1 == N) ? E
                        : offs[node + 1] + bsums[(node + 1) >> 10];
                for (int base = s; base < e; base += 32) {
                    int cnt = min(e - base, 32);
                    int2 ev = make_int2(0, 0);            // pad: row 0, w=0
                    if (l < cnt) ev = esrt[base + l];
                    for (int j = 0; j < cnt; j += 8) {
                        ushort4v v[8]; float w[8];
                        #pragma unroll
                        for (int q = 0; q < 8; ++q) {
                            int   sq = __shfl(ev.x, j + q, 32);
                            int   wb = __shfl(ev.y, j + q, 32);
                            w[q] = __int_as_float(wb);
                            v[q] = xr[(size_t)sq * 32 + l];
                        }
                        #pragma unroll
                        for (int q = 0; q < 8; ++q) {
                            acc.x += w[q] * bf2f(v[q][0]);
                            acc.y += w[q] * bf2f(v[q][1]);
                            acc.z += w[q] * bf2f(v[q][2]);
                            acc.w += w[q] * bf2f(v[q][3]);
                        }
                    }
                }
            }
            ushort4v o;
            o[0] = f2bf(acc.x); o[1] = f2bf(acc.y);
            o[2] = f2bf(acc.z); o[3] = f2bf(acc.w);
            int soff = m * 128 + (((l >> 1) ^ (m & 7)) << 3) + ((l & 1) << 2);
            *reinterpret_cast<ushort4v*>(&Hs[soff]) = o;
        }
    }
    __syncthreads();

    int wave = tid >> 6, lane = tid & 63;
    int r = lane & 15, kg = lane >> 4;
    int row0 = node0 + wave * 16;
    int mr = wave * 16 + r;

    short8 a[4];
    #pragma unroll
    for (int kt = 0; kt < 4; ++kt)
        a[kt] = *reinterpret_cast<const short8*>(
            &Hs[mr * 128 + (((kt * 4 + kg) ^ (r & 7)) << 3)]);

    f32x4 acc1[8];
    #pragma unroll
    for (int jt = 0; jt < 8; ++jt) acc1[jt] = {0.f, 0.f, 0.f, 0.f};

    #pragma unroll
    for (int jt = 0; jt < 8; ++jt) {
        #pragma unroll
        for (int kt = 0; kt < 4; ++kt) {
            short8 b = *reinterpret_cast<const short8*>(
                wtf1 + ((jt * 4 + kt) << 9) + (lane << 3));   // coalesced
            acc1[jt] = __builtin_amdgcn_mfma_f32_16x16x32_bf16(a[kt], b, acc1[jt], 0, 0, 0);
        }
    }

    #pragma unroll
    for (int jt = 0; jt < 8; ++jt) {
        float bias = b1[jt * 16 + r];
        int col = jt * 16 + r;
        #pragma unroll
        for (int reg = 0; reg < 4; ++reg) {
            int m2 = wave * 16 + kg * 4 + reg;
            float h = fmaxf(acc1[jt][reg] + bias, 0.0f);
            Hs[m2 * 128 + (((col >> 3) ^ (m2 & 7)) << 3) + (col & 7)] = f2bf(h);
        }
    }
    __syncthreads();

    short8 a2[4];
    #pragma unroll
    for (int kt = 0; kt < 4; ++kt)
        a2[kt] = *reinterpret_cast<const short8*>(
            &Hs[mr * 128 + (((kt * 4 + kg) ^ (r & 7)) << 3)]);

    f32x4 acc2[8];
    #pragma unroll
    for (int jt = 0; jt < 8; ++jt) acc2[jt] = {0.f, 0.f, 0.f, 0.f};

    #pragma unroll
    for (int jt = 0; jt < 8; ++jt) {
        #pragma unroll
        for (int kt = 0; kt < 4; ++kt) {
            short8 b = *reinterpret_cast<const short8*>(
                wtf2 + ((jt * 4 + kt) << 9) + (lane << 3));
            acc2[jt] = __builtin_amdgcn_mfma_f32_16x16x32_bf16(a2[kt], b, acc2[jt], 0, 0, 0);
        }
    }

    #pragma unroll
    for (int jt = 0; jt < 8; ++jt) {
        float bias = b2[jt * 16 + r];
        #pragma unroll
        for (int reg = 0; reg < 4; ++reg) {
            int orow = row0 + kg * 4 + reg;
            if (orow < N)
                y[(size_t)orow * 128 + jt * 16 + r] = acc2[jt][reg] + bias;
        }
    }
}

extern "C" void kernel_launch(void* const* d_in, const int* in_sizes, int n_in,
                              void* d_out, int out_size, void* d_ws, size_t ws_size,
                              hipStream_t stream) {
    const float* x  = (const float*)d_in[0];
    const int*   ei = (const int*)d_in[1];      // [2,E] as int32
    const float* ew = (const float*)d_in[2];
    const float* W1 = (const float*)d_in[3];
    const float* b1 = (const float*)d_in[4];
    const float* W2 = (const float*)d_in[5];
    const float* b2 = (const float*)d_in[6];
    float* y = (float*)d_out;

    int N = in_sizes[0] / 128;   // 100000
    int E = in_sizes[2];         // 600000
    const size_t ND = (size_t)N * 128;
    int nchunk = (N + 1023) / 1024;   // 98
    int n8 = (int)(ND / 8);
    int nxb = (n8 + 255) / 256;
    int nhist = (E + 255) / 256;

    char* ws = (char*)d_ws;
    size_t off = 0;
    auto bump = [&](size_t bytes) {
        void* p = ws + off;
        off += (bytes + 255) & ~(size_t)255;
        return p;
    };
    // zero-region first (one memset covers offs, czero, done)
    size_t zstart = off;
    int*            offs   = (int*)bump((size_t)N * 4);
    int*            czero  = (int*)bump((size_t)N * 4);
    int*            done   = (int*)bump(256);
    size_t zbytes = off - zstart;
    int*            bsums  = (int*)bump(1024);
    unsigned short* wtf1   = (unsigned short*)bump(128 * 128 * 2);
    unsigned short* wtf2   = (unsigned short*)bump(128 * 128 * 2);
    unsigned short* xb     = (unsigned short*)bump(ND * 2);          // 25.6 MB
    int2*           esrt   = (int2*)bump((size_t)E * 8);

    const int* src = ei;
    const int* dst = ei + E;

    hipMemsetAsync(ws + zstart, 0, zbytes, stream);
    prep_kernel<<<64 + nxb + nhist, 256, 0, stream>>>(
        W1, W2, x, dst, wtf1, wtf2, xb, offs, n8, E, nxb);
    scan_kernel<<<nchunk, 256, 0, stream>>>(offs, bsums, done, N, nchunk);
    scatter_kernel<<<nhist, 256, 0, stream>>>(src, dst, ew, offs, bsums,
                                              czero, esrt, E);
    fused_kernel<<<(N + 63) / 64, 256, 0, stream>>>(
        xb, offs, bsums, esrt, wtf1, wtf2, b1, b2, y, N, E);
}